// Round 13
// baseline (153.416 us; speedup 1.0000x reference)
//
#include <hip/hip_runtime.h>
#include <hip/hip_bf16.h>
#include <stdint.h>

// LocalSlidingWindowAttention: B=2, T=2048, D=1024, H=16, hd=64, keys j in [i, i+64].
// f32 in/out. Build (r13):
//   convert_all (proven) -> gemm1_dbf (NEW: 128x128, BK=32, 4-buf counted-vmcnt,
//   CROSS-TILE FRAGMENT DOUBLE-BUFFER — tile kt's MFMAs overlap tile kt+1's
//   ds_reads; no lgkm wait on the critical path; 64KB LDS -> 2 blocks/CU)
//   -> attn_mfma (r3, proven) -> gemm2_pipe (r12, proven: counted vmcnt(3)).
// r12 measured 145.99us total (best). gemm1 ladder: 43.7/46.0/42.3/~36(r6)/46.9/
//   ~38(r8-3cu). All share MfmaUtil~20% -> residual = in-wave ds_read->lgkm->MFMA
//   serial chain; frag-dbuf removes it. Fits VGPR only at 128^2 (acc64+frag64).

typedef short bf16x8 __attribute__((ext_vector_type(8)));
typedef float f32x4 __attribute__((ext_vector_type(4)));

typedef const __attribute__((address_space(1))) void* gptr_t;
typedef __attribute__((address_space(3))) void* lptr_t;

#define BAR()        asm volatile("s_barrier" ::: "memory")
#define WAIT_LGKM0() asm volatile("s_waitcnt lgkmcnt(0)" ::: "memory")

__device__ __forceinline__ float bf2f(short u) {
    union { float f; uint32_t i; } x;
    x.i = ((uint32_t)(uint16_t)u) << 16;
    return x.f;
}
__device__ __forceinline__ short f2bf(float f) {
    __hip_bfloat16 h = __float2bfloat16(f);  // RNE
    return *reinterpret_cast<short*>(&h);
}

// Convert x, w_qkv, w_out to bf16. 8 elems/thread.
__global__ __launch_bounds__(256)
void convert_all(const float* __restrict__ x, const float* __restrict__ wq,
                 const float* __restrict__ wo,
                 short* __restrict__ xb, short* __restrict__ wqb, short* __restrict__ wob) {
    int i = blockIdx.x * 256 + threadIdx.x;
    const float* src; short* dst; int o;
    if      (i <  524288) { src = x;  dst = xb;  o = i; }
    else if (i <  917504) { src = wq; dst = wqb; o = i - 524288; }
    else                  { src = wo; dst = wob; o = i - 917504; }
    const int e = o * 8;
    float4 a = *(const float4*)(src + e);
    float4 b = *(const float4*)(src + e + 4);
    short t[8];
    t[0] = f2bf(a.x); t[1] = f2bf(a.y); t[2] = f2bf(a.z); t[3] = f2bf(a.w);
    t[4] = f2bf(b.x); t[5] = f2bf(b.y); t[6] = f2bf(b.z); t[7] = f2bf(b.w);
    *(uint4*)(dst + e) = *(const uint4*)t;
}

// GEMM1 (r13): C[m,n] = sum_k A[m,k]*Bt[n,k] + bias[n], bf16 out. 128x128, BK=32.
// 256 threads = 4 waves (2M x 2N), per-wave 64x64, acc[4][4] (64 AGPR).
// LDS: 4 bufs x (128x32 A + 128x32 B) = 64 KiB -> 2 blocks/CU (launch_bounds 256,2).
// Frag double-buffer: sets fa/fb[2][4] (2x32 VGPR). Tile kt body:
//   {ds_read frags(kt+1) -> set kt+1&1; STAGE(kt+3); 16 MFMA from set kt&1
//    (no wait - regs loaded last tile); lgkm0+sched_barrier (rule #18);
//    vmcnt(4) [retires kt+2 -> kt+1-frag reads legal NEXT tile]; s_barrier}.
// Ledger (4 loads/tile): prologue stages 0,1,2 (12 out) -> vmcnt(4) retires 0,1.
//   Tile kt: issue kt+3 -> outstanding kt+2,kt+3 (8) -> vmcnt(4) retires kt+2.
//   Tail: nk-4 last issue; nk-3 vmcnt(0); nk-2 prefetch-only (no bar); nk-1 compute.
// Buf reuse: STAGE(kt+3) -> buf (kt-1)&3; its readers (frags(kt-1), read during
//   tile kt-2) lgkm-drained end-kt-2, then 2 barriers before the write. Published:
//   frags(kt+3) read during kt+2, retired end-kt+1 (vmcnt(4)), published end-kt+1 BAR.
// Swizzle (both-sides, r6/r8-validated): source chunk (g&3)^((g>>3)&3); read slot
//   sx8 = (qd^((l16>>1)&3))*8. Requires nk even, nk >= 6 (nk=32 here).
__global__ __launch_bounds__(256, 2)
void gemm1_dbf(const short* __restrict__ A, const short* __restrict__ Bt,
               const float* __restrict__ bias, short* __restrict__ C,
               int M, int N, int K) {
    __shared__ short As[4][128 * 32];   // 32 KiB
    __shared__ short Bs[4][128 * 32];   // 32 KiB

    const int tid  = threadIdx.x;
    const int lane = tid & 63;
    const int w    = tid >> 6;        // 0..3
    const int qd   = lane >> 4;       // 0..3
    const int l16  = lane & 15;
    const int wm   = w >> 1;          // 0..1 (64 rows each)
    const int wn   = w & 1;           // 0..1 (64 cols each)
    const int sx8  = (qd ^ ((l16 >> 1) & 3)) * 8;

    // XCD-chunked bijective swizzle (nwg=768, 768%8==0): chunk=96.
    const int nTn   = N >> 7;                     // 24
    const int chunk = gridDim.x >> 3;             // 96
    const int wg    = (blockIdx.x & 7) * chunk + (blockIdx.x >> 3);
    const int mt    = wg / nTn;
    const int nt    = wg - mt * nTn;
    const int mBase = mt << 7;
    const int nBase = nt << 7;

    // Staging: tile = 128x32 = 512 granules of 16B; 2 rounds of 256.
    // granule g = rr*256+tid: row=g>>2, stored slot=g&3, source chunk pre-XOR'd.
    const short* gA[2];
    const short* gB[2];
#pragma unroll
    for (int rr = 0; rr < 2; ++rr) {
        const int g    = rr * 256 + tid;
        const int row  = g >> 2;
        const int slot = (g & 3) ^ ((g >> 3) & 3);
        gA[rr] = A  + (size_t)(mBase + row) * K + slot * 8;
        gB[rr] = Bt + (size_t)(nBase + row) * K + slot * 8;
    }

    f32x4 acc[4][4] = {};
    bf16x8 fa[2][4], fb[2][4];        // frag double-buffer (static-indexed)
    const int nk = K >> 5;            // 32

#define STAGE(T) { const int b_ = (T) & 3; const size_t ka_ = (size_t)(T) * 32;   \
    _Pragma("unroll")                                                             \
    for (int rr = 0; rr < 2; ++rr)                                                \
        __builtin_amdgcn_global_load_lds((gptr_t)(gA[rr] + ka_),                  \
            (lptr_t)(&As[b_][0] + (rr * 256 + w * 64) * 8), 16, 0, 0);            \
    _Pragma("unroll")                                                             \
    for (int rr = 0; rr < 2; ++rr)                                                \
        __builtin_amdgcn_global_load_lds((gptr_t)(gB[rr] + ka_),                  \
            (lptr_t)(&Bs[b_][0] + (rr * 256 + w * 64) * 8), 16, 0, 0); }

#define PREF(KT, S) {                                                             \
    const short* Ab_ = &As[(KT) & 3][0];                                          \
    const short* Bb_ = &Bs[(KT) & 3][0];                                          \
    _Pragma("unroll")                                                             \
    for (int mi = 0; mi < 4; ++mi)                                                \
        fa[S][mi] = *(const bf16x8*)(Ab_ + (wm * 64 + mi * 16 + l16) * 32 + sx8); \
    _Pragma("unroll")                                                             \
    for (int ni = 0; ni < 4; ++ni)                                                \
        fb[S][ni] = *(const bf16x8*)(Bb_ + (wn * 64 + ni * 16 + l16) * 32 + sx8); }

#define MFMA16(S) {                                                               \
    __builtin_amdgcn_s_setprio(1);                                                \
    _Pragma("unroll")                                                             \
    for (int mi = 0; mi < 4; ++mi)                                                \
        _Pragma("unroll")                                                         \
        for (int ni = 0; ni < 4; ++ni)                                            \
            acc[mi][ni] = __builtin_amdgcn_mfma_f32_16x16x32_bf16(                \
                fa[S][mi], fb[S][ni], acc[mi][ni], 0, 0, 0);                      \
    __builtin_amdgcn_s_setprio(0); }

#define VM4 asm volatile("s_waitcnt vmcnt(4)" ::: "memory")
#define VM0 asm volatile("s_waitcnt vmcnt(0)" ::: "memory")
#define NOPW (void)0

#define FULL(KT, CUR, NXT, DO_ISSUE, ENDW, DO_PREF, DO_BAR) {                     \
    if (DO_PREF) PREF((KT) + 1, NXT)                                              \
    if (DO_ISSUE) STAGE((KT) + 3)                                                 \
    MFMA16(CUR)                                                                   \
    if (DO_PREF) { WAIT_LGKM0(); __builtin_amdgcn_sched_barrier(0); }             \
    ENDW;                                                                         \
    if (DO_BAR) BAR(); }

    // Prologue: stage 0,1,2; retire 0,1; load frags0 -> set0.
    STAGE(0) STAGE(1) STAGE(2)
    VM4;
    BAR();
    PREF(0, 0)
    WAIT_LGKM0();
    __builtin_amdgcn_sched_barrier(0);

    // Main pairs: kt = 0,2,..,nk-6 (sets alternate 0/1 by parity).
    for (int kt = 0; kt <= nk - 6; kt += 2) {
        FULL(kt,     0, 1, 1, VM4, 1, 1)
        FULL(kt + 1, 1, 0, 1, VM4, 1, 1)
    }
    // kt = nk-4 (even): last issuing tile.
    FULL(nk - 4, 0, 1, 1, VM4, 1, 1)
    // kt = nk-3: no issue; drain last tile's loads.
    FULL(nk - 3, 1, 0, 0, VM0, 1, 1)
    // kt = nk-2: prefetch-only (data already retired+published); no barrier needed.
    FULL(nk - 2, 0, 1, 0, NOPW, 1, 0)
    // kt = nk-1: compute only.
    FULL(nk - 1, 1, 0, 0, NOPW, 0, 0)
#undef FULL
#undef MFMA16
#undef PREF
#undef STAGE
#undef VM4
#undef VM0
#undef NOPW

    // Epilogue (r8/r11-validated mapping): n = ..+l16, m = ..+qd*4+rr.
#pragma unroll
    for (int nf = 0; nf < 4; ++nf) {
        const int n = nBase + wn * 64 + nf * 16 + l16;
        const float bv = bias[n];
#pragma unroll
        for (int mf = 0; mf < 4; ++mf)
#pragma unroll
            for (int rr = 0; rr < 4; ++rr) {
                const int m = mBase + wm * 64 + mf * 16 + qd * 4 + rr;
                C[(size_t)m * N + n] = f2bf(acc[mf][nf][rr] + bv);
            }
    }
}

// GEMM2 (r12, proven): out = attn @ w_out^T + b_out, f32 out/bias. 64x128 tile,
// BK=32, 3-deep counted-vmcnt pipeline, 1 bar/tile, both-sides XOR swizzle.
// LDS: 3 bufs x (64x32 A + 128x32 B) = 36 KiB -> 2 blocks/CU at 512 blocks.
__global__ __launch_bounds__(256)
void gemm2_pipe(const short* __restrict__ A, const short* __restrict__ Bt,
                const float* __restrict__ bias, float* __restrict__ C,
                int M, int N, int K) {
    __shared__ short As[3][64 * 32];    // 12 KB
    __shared__ short Bs[3][128 * 32];   // 24 KB

    const int tid  = threadIdx.x;
    const int lane = tid & 63;
    const int w    = tid >> 6;
    const int qd   = lane >> 4;
    const int l16  = lane & 15;
    const int wm   = w >> 1;          // 32 rows each
    const int wn   = w & 1;           // 64 cols each
    const int sx8  = (qd ^ ((l16 >> 1) & 3)) * 8;
    const int mBase = blockIdx.y * 64;
    const int nBase = blockIdx.x * 128;

    const short* gA;
    {
        const int g = tid;
        gA = A + (size_t)(mBase + (g >> 2)) * K + (((g & 3) ^ ((g >> 3) & 3)) * 8);
    }
    const short* gB[2];
#pragma unroll
    for (int rr = 0; rr < 2; ++rr) {
        const int g = rr * 256 + tid;
        gB[rr] = Bt + (size_t)(nBase + (g >> 2)) * K + (((g & 3) ^ ((g >> 3) & 3)) * 8);
    }

    f32x4 acc[2][4] = {};
    const int nk = K >> 5;            // 32

#define STAGE2(T) { const int b_ = (T) % 3; const size_t ka_ = (size_t)(T) * 32;  \
    __builtin_amdgcn_global_load_lds((gptr_t)(gA + ka_),                          \
        (lptr_t)(&As[b_][0] + (w * 64) * 8), 16, 0, 0);                           \
    _Pragma("unroll")                                                             \
    for (int rr = 0; rr < 2; ++rr)                                                \
        __builtin_amdgcn_global_load_lds((gptr_t)(gB[rr] + ka_),                  \
            (lptr_t)(&Bs[b_][0] + (rr * 256 + w * 64) * 8), 16, 0, 0); }

    STAGE2(0) STAGE2(1)
    asm volatile("s_waitcnt vmcnt(3)" ::: "memory");   // retire tile 0
    BAR();

#define TILE_BODY2(KT, DO_ISSUE, ENDWAIT, DO_BAR)                                 \
    {                                                                             \
        const int cur_ = (KT) % 3;                                                \
        const short* Ab_ = &As[cur_][0];                                          \
        const short* Bb_ = &Bs[cur_][0];                                          \
        bf16x8 af_[2], bfr_[4];                                                   \
        _Pragma("unroll")                                                         \
        for (int mi = 0; mi < 2; ++mi)                                            \
            af_[mi] = *(const bf16x8*)(Ab_ + (wm * 32 + mi * 16 + l16) * 32 + sx8); \
        _Pragma("unroll")                                                         \
        for (int ni = 0; ni < 4; ++ni)                                            \
            bfr_[ni] = *(const bf16x8*)(Bb_ + (wn * 64 + ni * 16 + l16) * 32 + sx8); \
        if (DO_ISSUE) STAGE2((KT) + 2)                                            \
        WAIT_LGKM0();                                                             \
        __builtin_amdgcn_sched_barrier(0);                                        \
        __builtin_amdgcn_s_setprio(1);                                            \
        _Pragma("unroll")                                                         \
        for (int mi = 0; mi < 2; ++mi)                                            \
            _Pragma("unroll")                                                     \
            for (int ni = 0; ni < 4; ++ni)                                        \
                acc[mi][ni] = __builtin_amdgcn_mfma_f32_16x16x32_bf16(            \
                    af_[mi], bfr_[ni], acc[mi][ni], 0, 0, 0);                     \
        __builtin_amdgcn_s_setprio(0);                                            \
        ENDWAIT;                                                                  \
        if (DO_BAR) BAR();                                                        \
    }

    for (int kt = 0; kt < nk - 2; ++kt)
        TILE_BODY2(kt, 1, asm volatile("s_waitcnt vmcnt(3)" ::: "memory"), 1)
    TILE_BODY2(nk - 2, 0, asm volatile("s_waitcnt vmcnt(0)" ::: "memory"), 1)
    TILE_BODY2(nk - 1, 0, (void)0, 0)
#undef TILE_BODY2
#undef STAGE2

#pragma unroll
    for (int ni = 0; ni < 4; ++ni) {
        const int n = nBase + wn * 64 + ni * 16 + l16;
        const float bv = bias[n];
#pragma unroll
        for (int mi = 0; mi < 2; ++mi)
#pragma unroll
            for (int rr = 0; rr < 4; ++rr) {
                const int m = mBase + wm * 32 + mi * 16 + qd * 4 + rr;
                C[(size_t)m * N + n] = acc[mi][ni][rr] + bv;
            }
    }
}

// MFMA attention (r3, proven). Block = 64 queries x head x batch; 4 waves.
__global__ __launch_bounds__(256)
void attn_mfma(const short* __restrict__ qkv, short* __restrict__ attn_out, int B, int T) {
    __shared__ short k_s[128 * 72];
    __shared__ short v_s[144 * 66];
    __shared__ short p_s[64 * 104];

    const int tid  = threadIdx.x;
    const int lane = tid & 63;
    const int w    = tid >> 6;
    const int qd   = lane >> 4;
    const int l16  = lane & 15;
    const int qs   = blockIdx.x * 64;
    const int h    = blockIdx.y;
    const int b    = blockIdx.z;
    const size_t rs   = 3072;
    const size_t base = (size_t)b * T * rs;
    const int qoff = h * 64, koff = 1024 + h * 64, voff = 2048 + h * 64;

#pragma unroll
    for (int i = 0; i < 5; ++i) {
        const int c   = tid + i * 256;
        const int row = c >> 3;
        if (row >= 144) break;
        const int ch = (c & 7) * 8;
        int gr = qs + row; if (gr > T - 1) gr = T - 1;
        uint4 uv = *(const uint4*)(qkv + base + (size_t)gr * rs + voff + ch);
        if (row < 128) {
            uint4 uk = *(const uint4*)(qkv + base + (size_t)gr * rs + koff + ch);
            *(uint4*)&k_s[row * 72 + ch] = uk;
        }
        const uint32_t* vp = (const uint32_t*)&uv;
        uint32_t* vd = (uint32_t*)&v_s[row * 66 + ch];
        vd[0] = vp[0]; vd[1] = vp[1]; vd[2] = vp[2]; vd[3] = vp[3];
    }
    __syncthreads();

    bf16x8 aq0, aq1;
    {
        const short* g = qkv + base + (size_t)(qs + 16 * w + l16) * rs + qoff + qd * 8;
        aq0 = *(const bf16x8*)(g);
        aq1 = *(const bf16x8*)(g + 32);
    }

    f32x4 sacc[5] = {};
#pragma unroll
    for (int u = 0; u < 5; ++u) {
        const int krow = 16 * (w + u) + l16;
        bf16x8 bk0 = *(const bf16x8*)&k_s[krow * 72 + qd * 8];
        bf16x8 bk1 = *(const bf16x8*)&k_s[krow * 72 + 32 + qd * 8];
        sacc[u] = __builtin_amdgcn_mfma_f32_16x16x32_bf16(aq0, bk0, sacc[u], 0, 0, 0);
        sacc[u] = __builtin_amdgcn_mfma_f32_16x16x32_bf16(aq1, bk1, sacc[u], 0, 0, 0);
    }

    const float scale = 0.125f;
    float pw[5][4];
    float inv[4];
#pragma unroll
    for (int r = 0; r < 4; ++r) {
        const int m = 4 * qd + r;
        float mx = -3.4e38f;
#pragma unroll
        for (int u = 0; u < 5; ++u) {
            const int rel = 16 * u + l16 - m;
            const int j   = qs + 16 * (w + u) + l16;
            const bool ok = (rel >= 0) & (rel <= 64) & (j < T);
            const float v = ok ? sacc[u][r] * scale : -3.4e38f;
            pw[u][r] = v;
            mx = fmaxf(mx, v);
        }
#pragma unroll
        for (int msk = 1; msk <= 8; msk <<= 1) mx = fmaxf(mx, __shfl_xor(mx, msk));
        float sum = 0.f;
#pragma unroll
        for (int u = 0; u < 5; ++u) {
            float e = (pw[u][r] <= -3.0e38f) ? 0.f : __expf(pw[u][r] - mx);
            pw[u][r] = e;
            sum += e;
        }
#pragma unroll
        for (int msk = 1; msk <= 8; msk <<= 1) sum += __shfl_xor(sum, msk);
        inv[r] = 1.0f / sum;
    }

#pragma unroll
    for (int u = 0; u < 5; ++u)
#pragma unroll
        for (int r = 0; r < 4; ++r)
            p_s[(16 * w + 4 * qd + r) * 104 + 16 * u + l16] = f2bf(pw[u][r] * inv[r]);
#pragma unroll
    for (int r = 0; r < 4; ++r)
        p_s[(16 * w + 4 * qd + r) * 104 + 80 + l16] = 0;
    // wave-private rows; same-wave RAW -> lgkmcnt wait, no barrier needed

    f32x4 oacc[4] = {};
#pragma unroll
    for (int ks = 0; ks < 3; ++ks) {
        bf16x8 ap = *(const bf16x8*)&p_s[(16 * w + l16) * 104 + ks * 32 + qd * 8];
#pragma unroll
        for (int dt = 0; dt < 4; ++dt) {
            short t[8];
#pragma unroll
            for (int j = 0; j < 8; ++j)
                t[j] = v_s[(16 * w + ks * 32 + qd * 8 + j) * 66 + 16 * dt + l16];
            bf16x8 bv = *(const bf16x8*)t;
            oacc[dt] = __builtin_amdgcn_mfma_f32_16x16x32_bf16(bv, ap, oacc[dt], 0, 0, 0);
        }
    }

    const size_t row = (size_t)(b * T + qs + 16 * w + l16);
#pragma unroll
    for (int dt = 0; dt < 4; ++dt) {
        short t[4];
#pragma unroll
        for (int r = 0; r < 4; ++r) t[r] = f2bf(oacc[dt][r]);
        *(uint2*)&attn_out[row * 1024 + h * 64 + dt * 16 + qd * 4] = *(const uint2*)t;
    }
}

extern "C" void kernel_launch(void* const* d_in, const int* in_sizes, int n_in,
                              void* d_out, int out_size, void* d_ws, size_t ws_size,
                              hipStream_t stream) {
    (void)in_sizes; (void)n_in; (void)out_size; (void)ws_size;
    const int B = 2, T = 2048, D = 1024;
    const int M = B * T;  // 4096

    char* ws = (char*)d_ws;
    size_t off = 0;
    short* xb   = (short*)(ws + off); off += (size_t)M * D * 2;       // 8.4 MB
    short* wqkb = (short*)(ws + off); off += (size_t)3 * D * D * 2;   // 6.3 MB
    short* wob  = (short*)(ws + off); off += (size_t)D * D * 2;       // 2.1 MB
    short* qkv  = (short*)(ws + off); off += (size_t)M * 3 * D * 2;   // 25.2 MB
    short* attn = (short*)(ws + off); off += (size_t)M * D * 2;       // 8.4 MB

    convert_all<<<dim3(4096), 256, 0, stream>>>(
        (const float*)d_in[0], (const float*)d_in[1], (const float*)d_in[3],
        xb, wqkb, wob);

    gemm1_dbf<<<dim3(768), 256, 0, stream>>>(
        xb, wqkb, (const float*)d_in[2], qkv, M, 3 * D, D);
    attn_mfma<<<dim3(T / 64, 16, B), 256, 0, stream>>>(qkv, attn, B, T);
    gemm2_pipe<<<dim3(D / 128, M / 64), 256, 0, stream>>>(
        attn, wob, (const float*)d_in[4], (float*)d_out, M, D, D);
}

// Round 14
// 146.202 us; speedup vs baseline: 1.0493x; 1.0493x over previous
//
#include <hip/hip_runtime.h>
#include <hip/hip_bf16.h>
#include <stdint.h>

// LocalSlidingWindowAttention: B=2, T=2048, D=1024, H=16, hd=64, keys j in [i, i+64].
// f32 in/out. Build (r14):
//   convert_all (proven) -> gemm1_fc (NEW GEOMETRY: 128x192 tile -> 512 blocks =
//   exactly 2/CU, FULL CU coverage; r8/r12-validated 1-bar counted-vmcnt pipeline,
//   4 bufs, 80KB LDS) -> attn_mfma (r3, proven) -> gemm2_pipe (r12, proven).
// Evidence: all gemm1 schedules (2-bar/1-bar/8-phase/3-CU/frag-dbuf) sit at
//   ~3.7 TF/CU; r6's 256^2 grid=192 left 64 CUs IDLE. gemm2 (512 blocks, 2/CU,
//   same structure) runs ~1.2+ PF. r13 frag-dbuf failed (43.5us, MfmaUtil still
//   21%, FETCH 2x from 128^2 tile). Fix = geometry: full coverage + 2/CU
//   co-residency + better FLOP/byte than 128^2 (192-col B panel).
// Ledger (5 loads/tile: A x2 rounds + B x3 rounds, per-wave uniform): prologue
//   stages 0,1,2 (15 out) -> vmcnt(10) retires t0. Tile kt: issue kt+3 (15 out)
//   -> vmcnt(10) retires exactly kt+1. Tail: vmcnt(5), vmcnt(0), none.
// Buf reuse: STAGE(kt+3) -> buf (kt-1)&3, readers drained pre-kt-1-MFMA and all
//   waves passed kt-1 end-bar before any kt-body issue. r12 total: 145.99us.

typedef short bf16x8 __attribute__((ext_vector_type(8)));
typedef float f32x4 __attribute__((ext_vector_type(4)));

typedef const __attribute__((address_space(1))) void* gptr_t;
typedef __attribute__((address_space(3))) void* lptr_t;

#define BAR()        asm volatile("s_barrier" ::: "memory")
#define WAIT_LGKM0() asm volatile("s_waitcnt lgkmcnt(0)" ::: "memory")

__device__ __forceinline__ float bf2f(short u) {
    union { float f; uint32_t i; } x;
    x.i = ((uint32_t)(uint16_t)u) << 16;
    return x.f;
}
__device__ __forceinline__ short f2bf(float f) {
    __hip_bfloat16 h = __float2bfloat16(f);  // RNE
    return *reinterpret_cast<short*>(&h);
}

// Convert x, w_qkv, w_out to bf16. 8 elems/thread.
__global__ __launch_bounds__(256)
void convert_all(const float* __restrict__ x, const float* __restrict__ wq,
                 const float* __restrict__ wo,
                 short* __restrict__ xb, short* __restrict__ wqb, short* __restrict__ wob) {
    int i = blockIdx.x * 256 + threadIdx.x;
    const float* src; short* dst; int o;
    if      (i <  524288) { src = x;  dst = xb;  o = i; }
    else if (i <  917504) { src = wq; dst = wqb; o = i - 524288; }
    else                  { src = wo; dst = wob; o = i - 917504; }
    const int e = o * 8;
    float4 a = *(const float4*)(src + e);
    float4 b = *(const float4*)(src + e + 4);
    short t[8];
    t[0] = f2bf(a.x); t[1] = f2bf(a.y); t[2] = f2bf(a.z); t[3] = f2bf(a.w);
    t[4] = f2bf(b.x); t[5] = f2bf(b.y); t[6] = f2bf(b.z); t[7] = f2bf(b.w);
    *(uint4*)(dst + e) = *(const uint4*)t;
}

// GEMM1 (r14): C[m,n] = sum_k A[m,k]*Bt[n,k] + bias[n], bf16 out. 128x192 tile,
// BK=32. 256 threads = 4 waves (2M x 2N): per-wave 64 rows x 96 cols, acc[4][6].
// LDS: 4 bufs x (128x32 A + 192x32 B) = 80 KiB -> exactly 2 blocks/CU.
// Grid 32x16 = 512 = exactly 2/CU, full coverage, 512%8==0 bijective XCD chunk.
// Per K-tile: {4 A + 6 B ds_read_b128 (swizzled); issue 5 gloads (tile kt+3);
//   lgkm0; 24 MFMA (setprio); vmcnt(10); s_barrier}.
// Swizzle (both-sides, r6/r8/r12-validated): source chunk (g&3)^((g>>3)&3);
//   read slot sx8 = (qd^((l16>>1)&3))*8 (const: all row-bases are mult of 16).
__global__ __launch_bounds__(256, 2)
void gemm1_fc(const short* __restrict__ A, const short* __restrict__ Bt,
              const float* __restrict__ bias, short* __restrict__ C,
              int M, int N, int K) {
    __shared__ short As[4][128 * 32];   // 32 KiB
    __shared__ short Bs[4][192 * 32];   // 48 KiB

    const int tid  = threadIdx.x;
    const int lane = tid & 63;
    const int w    = tid >> 6;        // 0..3
    const int qd   = lane >> 4;       // 0..3
    const int l16  = lane & 15;
    const int wm   = w >> 1;          // 0..1 (64 rows each)
    const int wn   = w & 1;           // 0..1 (96 cols each)
    const int sx8  = (qd ^ ((l16 >> 1) & 3)) * 8;

    // XCD-chunked bijective swizzle (nwg=512, 512%8==0): chunk=64.
    const int nTn   = N / 192;                    // 16
    const int chunk = gridDim.x >> 3;             // 64
    const int wg    = (blockIdx.x & 7) * chunk + (blockIdx.x >> 3);
    const int mt    = wg / nTn;                   // 0..31
    const int nt    = wg - mt * nTn;              // 0..15
    const int mBase = mt << 7;                    // *128
    const int nBase = nt * 192;

    // Staging: A tile 128x32 = 512 granules (2 rounds of 256); B tile 192x32 =
    // 768 granules (3 rounds). granule g: row=g>>2, stored slot=g&3, source
    // chunk pre-XOR'd (g&3)^((g>>3)&3) [= slot ^ ((row>>1)&3)].
    const short* gA[2];
    const short* gB[3];
#pragma unroll
    for (int rr = 0; rr < 2; ++rr) {
        const int g = rr * 256 + tid;
        gA[rr] = A + (size_t)(mBase + (g >> 2)) * K + (((g & 3) ^ ((g >> 3) & 3)) * 8);
    }
#pragma unroll
    for (int rr = 0; rr < 3; ++rr) {
        const int g = rr * 256 + tid;
        gB[rr] = Bt + (size_t)(nBase + (g >> 2)) * K + (((g & 3) ^ ((g >> 3) & 3)) * 8);
    }

    f32x4 acc[4][6] = {};
    const int nk = K >> 5;            // 32 (requires nk >= 4)

#define STAGE(T) { const int b_ = (T) & 3; const size_t ka_ = (size_t)(T) * 32;   \
    _Pragma("unroll")                                                             \
    for (int rr = 0; rr < 2; ++rr)                                                \
        __builtin_amdgcn_global_load_lds((gptr_t)(gA[rr] + ka_),                  \
            (lptr_t)(&As[b_][0] + (rr * 256 + w * 64) * 8), 16, 0, 0);            \
    _Pragma("unroll")                                                             \
    for (int rr = 0; rr < 3; ++rr)                                                \
        __builtin_amdgcn_global_load_lds((gptr_t)(gB[rr] + ka_),                  \
            (lptr_t)(&Bs[b_][0] + (rr * 256 + w * 64) * 8), 16, 0, 0); }

    // Prologue: stage tiles 0,1,2 (15 loads); vmcnt(10) retires tile 0.
    STAGE(0) STAGE(1) STAGE(2)
    asm volatile("s_waitcnt vmcnt(10)" ::: "memory");
    BAR();

#define TILE_BODY(KT, DO_ISSUE, ENDWAIT, DO_BAR)                                  \
    {                                                                             \
        const int cur_ = (KT) & 3;                                                \
        const short* Ab_ = &As[cur_][0];                                          \
        const short* Bb_ = &Bs[cur_][0];                                          \
        bf16x8 af_[4], bfr_[6];                                                   \
        _Pragma("unroll")                                                         \
        for (int mi = 0; mi < 4; ++mi)                                            \
            af_[mi] = *(const bf16x8*)(Ab_ + (wm * 64 + mi * 16 + l16) * 32 + sx8); \
        _Pragma("unroll")                                                         \
        for (int ni = 0; ni < 6; ++ni)                                            \
            bfr_[ni] = *(const bf16x8*)(Bb_ + (wn * 96 + ni * 16 + l16) * 32 + sx8); \
        if (DO_ISSUE) STAGE((KT) + 3)                                             \
        WAIT_LGKM0();                                                             \
        __builtin_amdgcn_sched_barrier(0);                                        \
        __builtin_amdgcn_s_setprio(1);                                            \
        _Pragma("unroll")                                                         \
        for (int mi = 0; mi < 4; ++mi)                                            \
            _Pragma("unroll")                                                     \
            for (int ni = 0; ni < 6; ++ni)                                        \
                acc[mi][ni] = __builtin_amdgcn_mfma_f32_16x16x32_bf16(            \
                    af_[mi], bfr_[ni], acc[mi][ni], 0, 0, 0);                     \
        __builtin_amdgcn_s_setprio(0);                                            \
        ENDWAIT;                                                                  \
        if (DO_BAR) BAR();                                                        \
    }

    // Main: tiles 0..nk-4 issue kt+3, vmcnt(10) retires kt+1.
    for (int kt = 0; kt < nk - 3; ++kt)
        TILE_BODY(kt, 1, asm volatile("s_waitcnt vmcnt(10)" ::: "memory"), 1)
    // Tail: nk-3 (10 out -> vmcnt(5) retires nk-2); nk-2 (vmcnt(0)); nk-1.
    TILE_BODY(nk - 3, 0, asm volatile("s_waitcnt vmcnt(5)" ::: "memory"), 1)
    TILE_BODY(nk - 2, 0, asm volatile("s_waitcnt vmcnt(0)" ::: "memory"), 1)
    TILE_BODY(nk - 1, 0, (void)0, 0)
#undef TILE_BODY
#undef STAGE

    // Epilogue: n = ..+l16 (lane-consecutive), m = ..+qd*4+rr (proven mapping).
#pragma unroll
    for (int nf = 0; nf < 6; ++nf) {
        const int n = nBase + wn * 96 + nf * 16 + l16;
        const float bv = bias[n];
#pragma unroll
        for (int mf = 0; mf < 4; ++mf)
#pragma unroll
            for (int rr = 0; rr < 4; ++rr) {
                const int m = mBase + wm * 64 + mf * 16 + qd * 4 + rr;
                C[(size_t)m * N + n] = f2bf(acc[mf][nf][rr] + bv);
            }
    }
}

// GEMM2 (r12, proven): out = attn @ w_out^T + b_out, f32 out/bias. 64x128 tile,
// BK=32, 3-deep counted-vmcnt pipeline, 1 bar/tile, both-sides XOR swizzle.
// LDS: 3 bufs x (64x32 A + 128x32 B) = 36 KiB -> 2 blocks/CU at 512 blocks.
__global__ __launch_bounds__(256)
void gemm2_pipe(const short* __restrict__ A, const short* __restrict__ Bt,
                const float* __restrict__ bias, float* __restrict__ C,
                int M, int N, int K) {
    __shared__ short As[3][64 * 32];    // 12 KB
    __shared__ short Bs[3][128 * 32];   // 24 KB

    const int tid  = threadIdx.x;
    const int lane = tid & 63;
    const int w    = tid >> 6;
    const int qd   = lane >> 4;
    const int l16  = lane & 15;
    const int wm   = w >> 1;          // 32 rows each
    const int wn   = w & 1;           // 64 cols each
    const int sx8  = (qd ^ ((l16 >> 1) & 3)) * 8;
    const int mBase = blockIdx.y * 64;
    const int nBase = blockIdx.x * 128;

    const short* gA;
    {
        const int g = tid;
        gA = A + (size_t)(mBase + (g >> 2)) * K + (((g & 3) ^ ((g >> 3) & 3)) * 8);
    }
    const short* gB[2];
#pragma unroll
    for (int rr = 0; rr < 2; ++rr) {
        const int g = rr * 256 + tid;
        gB[rr] = Bt + (size_t)(nBase + (g >> 2)) * K + (((g & 3) ^ ((g >> 3) & 3)) * 8);
    }

    f32x4 acc[2][4] = {};
    const int nk = K >> 5;            // 32

#define STAGE2(T) { const int b_ = (T) % 3; const size_t ka_ = (size_t)(T) * 32;  \
    __builtin_amdgcn_global_load_lds((gptr_t)(gA + ka_),                          \
        (lptr_t)(&As[b_][0] + (w * 64) * 8), 16, 0, 0);                           \
    _Pragma("unroll")                                                             \
    for (int rr = 0; rr < 2; ++rr)                                                \
        __builtin_amdgcn_global_load_lds((gptr_t)(gB[rr] + ka_),                  \
            (lptr_t)(&Bs[b_][0] + (rr * 256 + w * 64) * 8), 16, 0, 0); }

    STAGE2(0) STAGE2(1)
    asm volatile("s_waitcnt vmcnt(3)" ::: "memory");   // retire tile 0
    BAR();

#define TILE_BODY2(KT, DO_ISSUE, ENDWAIT, DO_BAR)                                 \
    {                                                                             \
        const int cur_ = (KT) % 3;                                                \
        const short* Ab_ = &As[cur_][0];                                          \
        const short* Bb_ = &Bs[cur_][0];                                          \
        bf16x8 af_[2], bfr_[4];                                                   \
        _Pragma("unroll")                                                         \
        for (int mi = 0; mi < 2; ++mi)                                            \
            af_[mi] = *(const bf16x8*)(Ab_ + (wm * 32 + mi * 16 + l16) * 32 + sx8); \
        _Pragma("unroll")                                                         \
        for (int ni = 0; ni < 4; ++ni)                                            \
            bfr_[ni] = *(const bf16x8*)(Bb_ + (wn * 64 + ni * 16 + l16) * 32 + sx8); \
        if (DO_ISSUE) STAGE2((KT) + 2)                                            \
        WAIT_LGKM0();                                                             \
        __builtin_amdgcn_sched_barrier(0);                                        \
        __builtin_amdgcn_s_setprio(1);                                            \
        _Pragma("unroll")                                                         \
        for (int mi = 0; mi < 2; ++mi)                                            \
            _Pragma("unroll")                                                     \
            for (int ni = 0; ni < 4; ++ni)                                        \
                acc[mi][ni] = __builtin_amdgcn_mfma_f32_16x16x32_bf16(            \
                    af_[mi], bfr_[ni], acc[mi][ni], 0, 0, 0);                     \
        __builtin_amdgcn_s_setprio(0);                                            \
        ENDWAIT;                                                                  \
        if (DO_BAR) BAR();                                                        \
    }

    for (int kt = 0; kt < nk - 2; ++kt)
        TILE_BODY2(kt, 1, asm volatile("s_waitcnt vmcnt(3)" ::: "memory"), 1)
    TILE_BODY2(nk - 2, 0, asm volatile("s_waitcnt vmcnt(0)" ::: "memory"), 1)
    TILE_BODY2(nk - 1, 0, (void)0, 0)
#undef TILE_BODY2
#undef STAGE2

#pragma unroll
    for (int ni = 0; ni < 4; ++ni) {
        const int n = nBase + wn * 64 + ni * 16 + l16;
        const float bv = bias[n];
#pragma unroll
        for (int mi = 0; mi < 2; ++mi)
#pragma unroll
            for (int rr = 0; rr < 4; ++rr) {
                const int m = mBase + wm * 32 + mi * 16 + qd * 4 + rr;
                C[(size_t)m * N + n] = acc[mi][ni][rr] + bv;
            }
    }
}

// MFMA attention (r3, proven). Block = 64 queries x head x batch; 4 waves.
__global__ __launch_bounds__(256)
void attn_mfma(const short* __restrict__ qkv, short* __restrict__ attn_out, int B, int T) {
    __shared__ short k_s[128 * 72];
    __shared__ short v_s[144 * 66];
    __shared__ short p_s[64 * 104];

    const int tid  = threadIdx.x;
    const int lane = tid & 63;
    const int w    = tid >> 6;
    const int qd   = lane >> 4;
    const int l16  = lane & 15;
    const int qs   = blockIdx.x * 64;
    const int h    = blockIdx.y;
    const int b    = blockIdx.z;
    const size_t rs   = 3072;
    const size_t base = (size_t)b * T * rs;
    const int qoff = h * 64, koff = 1024 + h * 64, voff = 2048 + h * 64;

#pragma unroll
    for (int i = 0; i < 5; ++i) {
        const int c   = tid + i * 256;
        const int row = c >> 3;
        if (row >= 144) break;
        const int ch = (c & 7) * 8;
        int gr = qs + row; if (gr > T - 1) gr = T - 1;
        uint4 uv = *(const uint4*)(qkv + base + (size_t)gr * rs + voff + ch);
        if (row < 128) {
            uint4 uk = *(const uint4*)(qkv + base + (size_t)gr * rs + koff + ch);
            *(uint4*)&k_s[row * 72 + ch] = uk;
        }
        const uint32_t* vp = (const uint32_t*)&uv;
        uint32_t* vd = (uint32_t*)&v_s[row * 66 + ch];
        vd[0] = vp[0]; vd[1] = vp[1]; vd[2] = vp[2]; vd[3] = vp[3];
    }
    __syncthreads();

    bf16x8 aq0, aq1;
    {
        const short* g = qkv + base + (size_t)(qs + 16 * w + l16) * rs + qoff + qd * 8;
        aq0 = *(const bf16x8*)(g);
        aq1 = *(const bf16x8*)(g + 32);
    }

    f32x4 sacc[5] = {};
#pragma unroll
    for (int u = 0; u < 5; ++u) {
        const int krow = 16 * (w + u) + l16;
        bf16x8 bk0 = *(const bf16x8*)&k_s[krow * 72 + qd * 8];
        bf16x8 bk1 = *(const bf16x8*)&k_s[krow * 72 + 32 + qd * 8];
        sacc[u] = __builtin_amdgcn_mfma_f32_16x16x32_bf16(aq0, bk0, sacc[u], 0, 0, 0);
        sacc[u] = __builtin_amdgcn_mfma_f32_16x16x32_bf16(aq1, bk1, sacc[u], 0, 0, 0);
    }

    const float scale = 0.125f;
    float pw[5][4];
    float inv[4];
#pragma unroll
    for (int r = 0; r < 4; ++r) {
        const int m = 4 * qd + r;
        float mx = -3.4e38f;
#pragma unroll
        for (int u = 0; u < 5; ++u) {
            const int rel = 16 * u + l16 - m;
            const int j   = qs + 16 * (w + u) + l16;
            const bool ok = (rel >= 0) & (rel <= 64) & (j < T);
            const float v = ok ? sacc[u][r] * scale : -3.4e38f;
            pw[u][r] = v;
            mx = fmaxf(mx, v);
        }
#pragma unroll
        for (int msk = 1; msk <= 8; msk <<= 1) mx = fmaxf(mx, __shfl_xor(mx, msk));
        float sum = 0.f;
#pragma unroll
        for (int u = 0; u < 5; ++u) {
            float e = (pw[u][r] <= -3.0e38f) ? 0.f : __expf(pw[u][r] - mx);
            pw[u][r] = e;
            sum += e;
        }
#pragma unroll
        for (int msk = 1; msk <= 8; msk <<= 1) sum += __shfl_xor(sum, msk);
        inv[r] = 1.0f / sum;
    }

#pragma unroll
    for (int u = 0; u < 5; ++u)
#pragma unroll
        for (int r = 0; r < 4; ++r)
            p_s[(16 * w + 4 * qd + r) * 104 + 16 * u + l16] = f2bf(pw[u][r] * inv[r]);
#pragma unroll
    for (int r = 0; r < 4; ++r)
        p_s[(16 * w + 4 * qd + r) * 104 + 80 + l16] = 0;
    // wave-private rows; same-wave RAW -> lgkmcnt wait, no barrier needed

    f32x4 oacc[4] = {};
#pragma unroll
    for (int ks = 0; ks < 3; ++ks) {
        bf16x8 ap = *(const bf16x8*)&p_s[(16 * w + l16) * 104 + ks * 32 + qd * 8];
#pragma unroll
        for (int dt = 0; dt < 4; ++dt) {
            short t[8];
#pragma unroll
            for (int j = 0; j < 8; ++j)
                t[j] = v_s[(16 * w + ks * 32 + qd * 8 + j) * 66 + 16 * dt + l16];
            bf16x8 bv = *(const bf16x8*)t;
            oacc[dt] = __builtin_amdgcn_mfma_f32_16x16x32_bf16(bv, ap, oacc[dt], 0, 0, 0);
        }
    }

    const size_t row = (size_t)(b * T + qs + 16 * w + l16);
#pragma unroll
    for (int dt = 0; dt < 4; ++dt) {
        short t[4];
#pragma unroll
        for (int r = 0; r < 4; ++r) t[r] = f2bf(oacc[dt][r]);
        *(uint2*)&attn_out[row * 1024 + h * 64 + dt * 16 + qd * 4] = *(const uint2*)t;
    }
}

extern "C" void kernel_launch(void* const* d_in, const int* in_sizes, int n_in,
                              void* d_out, int out_size, void* d_ws, size_t ws_size,
                              hipStream_t stream) {
    (void)in_sizes; (void)n_in; (void)out_size; (void)ws_size;
    const int B = 2, T = 2048, D = 1024;
    const int M = B * T;  // 4096

    char* ws = (char*)d_ws;
    size_t off = 0;
    short* xb   = (short*)(ws + off); off += (size_t)M * D * 2;       // 8.4 MB
    short* wqkb = (short*)(ws + off); off += (size_t)3 * D * D * 2;   // 6.3 MB
    short* wob  = (short*)(ws + off); off += (size_t)D * D * 2;       // 2.1 MB
    short* qkv  = (short*)(ws + off); off += (size_t)M * 3 * D * 2;   // 25.2 MB
    short* attn = (short*)(ws + off); off += (size_t)M * D * 2;       // 8.4 MB

    convert_all<<<dim3(4096), 256, 0, stream>>>(
        (const float*)d_in[0], (const float*)d_in[1], (const float*)d_in[3],
        xb, wqkb, wob);

    gemm1_fc<<<dim3(512), 256, 0, stream>>>(
        xb, wqkb, (const float*)d_in[2], qkv, M, 3 * D, D);
    attn_mfma<<<dim3(T / 64, 16, B), 256, 0, stream>>>(qkv, attn, B, T);
    gemm2_pipe<<<dim3(D / 128, M / 64), 256, 0, stream>>>(
        attn, wob, (const float*)d_in[4], (float*)d_out, M, D, D);
}